// Round 5
// baseline (820.707 us; speedup 1.0000x reference)
//
#include <hip/hip_runtime.h>
#include <hip/hip_bf16.h>

// Shapes (fixed by the reference)
#define Bq 4
#define Lq 1024
#define Dq 1024
#define Hq 16
#define HDq 64
#define Fq 4096
#define Mq (Bq*Lq)   // 4096 rows of activations

typedef unsigned short u16;
using short8  = __attribute__((ext_vector_type(8))) short;
using floatx4 = __attribute__((ext_vector_type(4))) float;

__device__ __forceinline__ float b2f(u16 u) {
  union { unsigned int i; float f; } v; v.i = ((unsigned int)u) << 16; return v.f;
}
__device__ __forceinline__ u16 f2b(float f) {
  union { float f; unsigned int i; } v; v.f = f;
  unsigned int x = v.i;
  unsigned int r = x + 0x7fffu + ((x >> 16) & 1u);
  return (u16)(r >> 16);
}

// split f32 -> hi/lo bf16 pair (v ~= hi + lo, residual ~2^-18 |v|)
__device__ __forceinline__ void split2(float v, u16& hi, u16& lo) {
  hi = f2b(v);
  lo = f2b(v - b2f(hi));
}

// ---------------------------------------------------------------------------
// f32 -> bf16 conversion. n4 must be a multiple of 4.
// ---------------------------------------------------------------------------
__launch_bounds__(256)
__global__ void cvt_f32_bf16(const float* __restrict__ s, u16* __restrict__ d, int n4) {
  const int i = (blockIdx.x * 256 + threadIdx.x) * 4;
  if (i < n4) {
    float4 v = *(const float4*)(s + i);
    ushort4 o;
    o.x = f2b(v.x); o.y = f2b(v.y); o.z = f2b(v.z); o.w = f2b(v.w);
    *(ushort4*)(d + i) = o;
  }
}

// ---------------------------------------------------------------------------
// GEMM: C[M,N] = A[M,K] * B[N,K]^T + bias[N]   (A,B bf16 K-contiguous,
// bias f32, C templated f32/bf16). 128x128 tile, BK=32, 4 waves,
// 4x4 16x16x32 bf16 MFMA. Register staging (m93-style).
// ---------------------------------------------------------------------------
template<bool RELU, typename OutT>
__launch_bounds__(256)
__global__ void gemm_bt(const u16* __restrict__ A, int lda,
                        const u16* __restrict__ B, int ldb,
                        const float* __restrict__ bias,
                        OutT* __restrict__ C, int ldc,
                        int K) {
  __shared__ __align__(16) u16 As[128 * 32];
  __shared__ __align__(16) u16 Bs[128 * 32];
  const int tid  = threadIdx.x;
  const int m0   = blockIdx.y * 128;
  const int n0   = blockIdx.x * 128;
  const int lane = tid & 63;
  const int wave = tid >> 6;
  const int wm   = (wave >> 1) * 64;
  const int wn   = (wave & 1) * 64;
  const int lrow = lane & 15;
  const int lk   = (lane >> 4) * 8;     // k-offset (elements) of this quad

  const int c0 = tid, c1 = tid + 256;
  const int ar0 = c0 >> 2, ac0 = (c0 & 3) * 8;
  const int ar1 = c1 >> 2, ac1 = (c1 & 3) * 8;

  floatx4 acc[4][4] = {};

  for (int k0 = 0; k0 < K; k0 += 32) {
    short8 va0 = *(const short8*)(A + (size_t)(m0 + ar0) * lda + k0 + ac0);
    short8 va1 = *(const short8*)(A + (size_t)(m0 + ar1) * lda + k0 + ac1);
    short8 vb0 = *(const short8*)(B + (size_t)(n0 + ar0) * ldb + k0 + ac0);
    short8 vb1 = *(const short8*)(B + (size_t)(n0 + ar1) * ldb + k0 + ac1);
    *(short8*)&As[c0 * 8] = va0;
    *(short8*)&As[c1 * 8] = va1;
    *(short8*)&Bs[c0 * 8] = vb0;
    *(short8*)&Bs[c1 * 8] = vb1;
    __syncthreads();

    short8 af[4], bf[4];
#pragma unroll
    for (int t = 0; t < 4; ++t) {
      af[t] = *(const short8*)&As[(wm + t * 16 + lrow) * 32 + lk];
      bf[t] = *(const short8*)&Bs[(wn + t * 16 + lrow) * 32 + lk];
    }
#pragma unroll
    for (int i = 0; i < 4; ++i)
#pragma unroll
      for (int j = 0; j < 4; ++j)
        acc[i][j] = __builtin_amdgcn_mfma_f32_16x16x32_bf16(af[i], bf[j], acc[i][j], 0, 0, 0);
    __syncthreads();
  }

  // epilogue: D row = quad*4 + reg, col = lane&15  (verified m89/m91 layout)
#pragma unroll
  for (int i = 0; i < 4; ++i) {
    const int row = m0 + wm + i * 16 + (lane >> 4) * 4;
#pragma unroll
    for (int j = 0; j < 4; ++j) {
      const int col = n0 + wn + j * 16 + lrow;
      const float bv = bias[col];
#pragma unroll
      for (int r = 0; r < 4; ++r) {
        float v = acc[i][j][r] + bv;
        if (RELU) v = v > 0.f ? v : 0.f;
        if constexpr (sizeof(OutT) == 4) C[(size_t)(row + r) * ldc + col] = v;
        else                             C[(size_t)(row + r) * ldc + col] = f2b(v);
      }
    }
  }
}

// ---------------------------------------------------------------------------
// Transpose V slice of f32 QKV into bf16 Vt[b][h][d][kpos]
// ---------------------------------------------------------------------------
__launch_bounds__(256)
__global__ void transpose_v(const float* __restrict__ qkv, u16* __restrict__ vt) {
  __shared__ __align__(16) float t[64][65];
  const int kt = blockIdx.x;   // 16 k-tiles
  const int h  = blockIdx.y;   // 16 heads
  const int b  = blockIdx.z;   // 4 batch
  const int tid = threadIdx.x;
#pragma unroll
  for (int i = 0; i < 16; ++i) {
    int e = i * 256 + tid;
    int kk = e >> 6, d = e & 63;
    t[kk][d] = qkv[((size_t)(b * Lq + kt * 64 + kk)) * (3 * Dq) + 2 * Dq + h * HDq + d];
  }
  __syncthreads();
#pragma unroll
  for (int i = 0; i < 16; ++i) {
    int e = i * 256 + tid;
    int drow = e >> 6, kcol = e & 63;
    vt[(((size_t)(b * Hq + h)) * HDq + drow) * Lq + kt * 64 + kcol] = f2b(t[kcol][drow]);
  }
}

// ---------------------------------------------------------------------------
// Fused attention. Q,K read as f32 and split into hi/lo bf16 so logits are
// ~f32-accurate (attn_w is a graded output). S in 64KB LDS, XOR-swizzled.
// attn_w written f32 into d_out; ctx bf16.
// ---------------------------------------------------------------------------
__device__ __forceinline__ int sw_idx(int m, int c) {
  return m * 1024 + (c ^ ((m & 3) * 8));
}

__device__ __forceinline__ void load_split8(const float* p, short8& hi, short8& lo) {
  float4 a = *(const float4*)p;
  float4 b = *(const float4*)(p + 4);
  float v[8] = {a.x, a.y, a.z, a.w, b.x, b.y, b.z, b.w};
#pragma unroll
  for (int j = 0; j < 8; ++j) {
    u16 h, l; split2(v[j], h, l);
    hi[j] = (short)h; lo[j] = (short)l;
  }
}

__launch_bounds__(256)
__global__ void attn_kernel(const float* __restrict__ qkv,
                            const u16* __restrict__ vt,
                            const float* __restrict__ mask,
                            float* __restrict__ attn_w,  // [B,H,L,L] f32 (d_out)
                            u16* __restrict__ ctx) {     // [B*L, D] bf16
  __shared__ __align__(16) float S[16 * 1024];   // 64KB exactly
  const int qt  = blockIdx.x;          // 64 q-tiles
  const int h   = blockIdx.y;
  const int b   = blockIdx.z;
  const int tid = threadIdx.x;
  const int lane = tid & 63, wave = tid >> 6;
  const int lrow = lane & 15, quad = lane >> 4;
  const int q0 = qt * 16;

  // --- phase 1: scores, split-precision QK^T ---
  const float* qbase = qkv + ((size_t)(b * Lq + q0 + lrow)) * (3 * Dq) + h * HDq + quad * 8;
  short8 aqh0, aql0, aqh1, aql1;
  load_split8(qbase,      aqh0, aql0);   // d = quad*8 + [0,8)
  load_split8(qbase + 32, aqh1, aql1);   // d = 32 + quad*8 + [0,8)

  const float* kbase = qkv + (size_t)(b * Lq) * (3 * Dq) + Dq + h * HDq + quad * 8;
  for (int i = 0; i < 16; ++i) {
    const int n0 = wave * 256 + i * 16;
    const float* kb = kbase + (size_t)(n0 + lrow) * (3 * Dq);
    short8 kh0, kl0, kh1, kl1;
    load_split8(kb,      kh0, kl0);
    load_split8(kb + 32, kh1, kl1);
    floatx4 sc = {};
    sc = __builtin_amdgcn_mfma_f32_16x16x32_bf16(aqh0, kh0, sc, 0, 0, 0);
    sc = __builtin_amdgcn_mfma_f32_16x16x32_bf16(aqh0, kl0, sc, 0, 0, 0);
    sc = __builtin_amdgcn_mfma_f32_16x16x32_bf16(aql0, kh0, sc, 0, 0, 0);
    sc = __builtin_amdgcn_mfma_f32_16x16x32_bf16(aqh1, kh1, sc, 0, 0, 0);
    sc = __builtin_amdgcn_mfma_f32_16x16x32_bf16(aqh1, kl1, sc, 0, 0, 0);
    sc = __builtin_amdgcn_mfma_f32_16x16x32_bf16(aql1, kh1, sc, 0, 0, 0);
#pragma unroll
    for (int r = 0; r < 4; ++r)
      S[sw_idx(quad * 4 + r, n0 + lrow)] = sc[r] * 0.125f;
  }
  __syncthreads();

  // --- phase 2: softmax (16 threads per row, stride 16) ---
  const int row = tid >> 4, idx = tid & 15;
  const float* mrow = mask + (size_t)(q0 + row) * Lq;
  float mx = -1e30f;
  for (int j = 0; j < 64; ++j) {
    const int c = idx + j * 16;
    float v = S[sw_idx(row, c)] + mrow[c];
    S[sw_idx(row, c)] = v;
    mx = fmaxf(mx, v);
  }
#pragma unroll
  for (int s = 1; s < 16; s <<= 1) mx = fmaxf(mx, __shfl_xor(mx, s, 16));
  float sum = 0.f;
  for (int j = 0; j < 64; ++j) {
    const int c = idx + j * 16;
    sum += __expf(S[sw_idx(row, c)] - mx);
  }
#pragma unroll
  for (int s = 1; s < 16; s <<= 1) sum += __shfl_xor(sum, s, 16);
  const float scl = 1.f / sum;

  // normalize in LDS + write attn_w (f32) straight into d_out
  float* wrow = attn_w + (((size_t)(b * Hq + h)) * Lq + q0 + row) * Lq;
  for (int j = 0; j < 64; ++j) {
    const int c = idx + j * 16;
    float w = __expf(S[sw_idx(row, c)] - mx) * scl;
    S[sw_idx(row, c)] = w;
    wrow[c] = w;
  }
  __syncthreads();

  // --- phase 3: ctx = P @ V ; wave w owns d-range [w*16, w*16+16) ---
  const u16* vbase = vt + ((((size_t)(b * Hq + h)) * HDq) + wave * 16 + lrow) * Lq + quad * 8;
  floatx4 o = {};
  for (int kc = 0; kc < Lq; kc += 32) {
    const float* ps = &S[sw_idx(lrow, kc + quad * 8)];
    short8 ap;
#pragma unroll
    for (int j = 0; j < 8; ++j) ap[j] = (short)f2b(ps[j]);
    short8 bv = *(const short8*)(vbase + kc);
    o = __builtin_amdgcn_mfma_f32_16x16x32_bf16(ap, bv, o, 0, 0, 0);
  }
#pragma unroll
  for (int r = 0; r < 4; ++r) {
    const int qrow = q0 + quad * 4 + r;
    ctx[((size_t)(b * Lq) + qrow) * Dq + h * HDq + wave * 16 + lrow] = f2b(o[r]);
  }
}

// ---------------------------------------------------------------------------
// Residual add + LayerNorm, one block per row of 1024, f32 math.
// a,res bf16; g,be f32; out templated (bf16 intermediate / f32 final).
// Safe for out == res.
// ---------------------------------------------------------------------------
template<typename OutT>
__launch_bounds__(256)
__global__ void add_ln(const u16* __restrict__ a, const u16* __restrict__ res,
                       const float* __restrict__ g, const float* __restrict__ be,
                       OutT* __restrict__ out) {
  const int rowi = blockIdx.x;
  const int tid = threadIdx.x;
  const u16* pa = a   + (size_t)rowi * Dq + tid * 4;
  const u16* pr = res + (size_t)rowi * Dq + tid * 4;
  ushort4 va = *(const ushort4*)pa;
  ushort4 vr = *(const ushort4*)pr;
  float v[4];
  float s = 0.f, s2 = 0.f;
#pragma unroll
  for (int j = 0; j < 4; ++j) {
    float x = b2f(((const u16*)&va)[j]) + b2f(((const u16*)&vr)[j]);
    v[j] = x; s += x; s2 += x * x;
  }
#pragma unroll
  for (int m = 1; m < 64; m <<= 1) { s += __shfl_xor(s, m, 64); s2 += __shfl_xor(s2, m, 64); }
  __shared__ float rs[4], rs2[4];
  const int wave = tid >> 6, lane = tid & 63;
  if (lane == 0) { rs[wave] = s; rs2[wave] = s2; }
  __syncthreads();
  s  = rs[0] + rs[1] + rs[2] + rs[3];
  s2 = rs2[0] + rs2[1] + rs2[2] + rs2[3];
  const float mean = s * (1.f / Dq);
  const float var  = s2 * (1.f / Dq) - mean * mean;
  const float rstd = rsqrtf(var + 1e-5f);
  float4 vg = *(const float4*)(g + tid * 4);
  float4 vb = *(const float4*)(be + tid * 4);
  float y0 = (v[0] - mean) * rstd * vg.x + vb.x;
  float y1 = (v[1] - mean) * rstd * vg.y + vb.y;
  float y2 = (v[2] - mean) * rstd * vg.z + vb.z;
  float y3 = (v[3] - mean) * rstd * vg.w + vb.w;
  if constexpr (sizeof(OutT) == 4) {
    float4 o = {y0, y1, y2, y3};
    *(float4*)(out + (size_t)rowi * Dq + tid * 4) = o;
  } else {
    ushort4 o;
    ((u16*)&o)[0] = f2b(y0); ((u16*)&o)[1] = f2b(y1);
    ((u16*)&o)[2] = f2b(y2); ((u16*)&o)[3] = f2b(y3);
    *(ushort4*)(out + (size_t)rowi * Dq + tid * 4) = o;
  }
}

// ---------------------------------------------------------------------------
extern "C" void kernel_launch(void* const* d_in, const int* in_sizes, int n_in,
                              void* d_out, int out_size, void* d_ws, size_t ws_size,
                              hipStream_t stream) {
  // Inputs are float32 (per the reference's setup_inputs).
  const float* x    = (const float*)d_in[0];
  const float* mask = (const float*)d_in[1];
  const float* win  = (const float*)d_in[2];
  const float* bin  = (const float*)d_in[3];
  const float* wo   = (const float*)d_in[4];
  const float* bo   = (const float*)d_in[5];
  const float* w1   = (const float*)d_in[6];
  const float* b1   = (const float*)d_in[7];
  const float* w2   = (const float*)d_in[8];
  const float* b2   = (const float*)d_in[9];
  const float* g1   = (const float*)d_in[10];
  const float* be1  = (const float*)d_in[11];
  const float* g2   = (const float*)d_in[12];
  const float* be2  = (const float*)d_in[13];

  // Outputs are float32 (reference output dtype).
  float* out0  = (float*)d_out;                       // [4,1024,1024]
  float* attnw = out0 + (size_t)Bq * Lq * Dq;         // [4,16,1024,1024]

  // Workspace layout (u16 units). Total 54,525,952 u16 = 104 MiB.
  u16*   ws   = (u16*)d_ws;
  u16*   xb   = ws;                                    // [0 .. 4.19M)
  float* qkvf = (float*)(ws + (size_t)4194304);        // f32 [4096,3072] = 25.17M u16
  u16*   vtb  = ws + (size_t)29360128;                 // 4.19M
  u16*   ctx  = ws + (size_t)33554432;                 // 4.19M
  u16*   aout = ws + (size_t)37748736;                 // 4.19M
  u16*   winb = ws + (size_t)41943040;                 // 3.15M
  u16*   wob  = ws + (size_t)45088768;                 // 1.05M
  u16*   w1b  = ws + (size_t)46137344;                 // 4.19M
  u16*   w2b  = ws + (size_t)50331648;                 // 4.19M
  u16*   y1   = aout;                                  // LN1 in-place over aout
  u16*   h1   = ws + (size_t)4194304;                  // aliases dead qkvf region
  u16*   ff   = ctx;                                   // aliases dead ctx

  // 0. f32 -> bf16 conversions of GEMM operands
  cvt_f32_bf16<<<4194304 / 1024, 256, 0, stream>>>(x,   xb,   4194304);
  cvt_f32_bf16<<<3145728 / 1024, 256, 0, stream>>>(win, winb, 3145728);
  cvt_f32_bf16<<<1048576 / 1024, 256, 0, stream>>>(wo,  wob,  1048576);
  cvt_f32_bf16<<<4194304 / 1024, 256, 0, stream>>>(w1,  w1b,  4194304);
  cvt_f32_bf16<<<4194304 / 1024, 256, 0, stream>>>(w2,  w2b,  4194304);

  // 1. QKV = x @ Win^T + bin   -> f32 (precision for attn_w path)
  gemm_bt<false, float><<<dim3(3 * Dq / 128, Mq / 128), 256, 0, stream>>>(
      xb, Dq, winb, Dq, bin, qkvf, 3 * Dq, Dq);
  // 2. Vt (bf16)
  transpose_v<<<dim3(16, Hq, Bq), 256, 0, stream>>>(qkvf, vtb);
  // 3. attention: attn_w (f32 -> d_out) and ctx (bf16)
  attn_kernel<<<dim3(Lq / 16, Hq, Bq), 256, 0, stream>>>(qkvf, vtb, mask, attnw, ctx);
  // 4. out_proj
  gemm_bt<false, u16><<<dim3(Dq / 128, Mq / 128), 256, 0, stream>>>(
      ctx, Dq, wob, Dq, bo, aout, Dq, Dq);
  // 5. LN1(x + attn_out) -> y1 bf16 (in-place over aout)
  add_ln<u16><<<Mq, 256, 0, stream>>>(xb, aout, g1, be1, y1);
  // 6. lin1 + ReLU   (lin1_w is (F,D): ldb = Dq)
  gemm_bt<true, u16><<<dim3(Fq / 128, Mq / 128), 256, 0, stream>>>(
      y1, Dq, w1b, Dq, b1, h1, Fq, Dq);
  // 7. lin2          (lin2_w is (D,F): ldb = Fq)
  gemm_bt<false, u16><<<dim3(Dq / 128, Mq / 128), 256, 0, stream>>>(
      h1, Fq, w2b, Fq, b2, ff, Dq, Fq);
  // 8. LN2(y1 + ff) -> out0 (f32)
  add_ln<float><<<Mq, 256, 0, stream>>>(y1, ff, g2, be2, out0);
}